// Round 7
// baseline (147.033 us; speedup 1.0000x reference)
//
#include <hip/hip_runtime.h>

// ETNN layer, N=50000 cells, HID=64, DEG=16 neighbors, 4 nodes/cell, sp=3.
//
// Bilinear split of the per-pair message MLP:
//   x@W1 = f_i@W1[0:64] + f_j@W1[64:128] + geom*W1[128]
// -> aux    : positions passthrough + weight pre-swizzle (SEPARATE LAUNCH:
//             prep_pq reads w1pq, so it must be produced in a prior kernel —
//             intra-launch block ordering is undefined)
// -> prep_pq: feat fp32->bf16 (featb) + centroids + P,Q = feat@[W1top|W1bot]
// -> gather : ONE WAVE PER CELL, parallel over (neighbor d, colgroup cg):
//             s[i] = mean_d silu(P[i] + Q[nbr[i,d]] + g*w1L + b1)
// -> tail   : msg = s@W2+b2; hu = silu([feat|msg]@Wu1+bu1); out = feat+hu@Wu2+bu2
//
// MFMA layouts (HW-verified): A[m=lane&15][k=quad*8+j], B[k=quad*8+j][n=lane&15],
// D[row=quad*4+reg][col=lane&15]. Transposed stages put weights in A so D cols
// land 4-consecutive per lane (packed uint2 stores). Wave-private LDS
// round-trips ordered by __threadfence_block + may_alias types.

#define DEG 16

typedef __attribute__((ext_vector_type(8))) short short8;   // 8 bf16
typedef __attribute__((ext_vector_type(4))) float f32x4;    // MFMA acc
typedef uint2 uint2_a __attribute__((may_alias));
typedef uint4 uint4_a __attribute__((may_alias));

union HbRd { uint4_a u; short8 s; };
union Frag { short8 s; uint4 u; };

__device__ __forceinline__ unsigned f2bf(float f) {
  unsigned u = __float_as_uint(f);
  return (u + 0x7FFFu + ((u >> 16) & 1u)) >> 16;   // RNE fp32->bf16
}
__device__ __forceinline__ float bf2f(unsigned bits16) {
  return __uint_as_float(bits16 << 16);
}
__device__ __forceinline__ float silu(float h) {
  return h / (1.f + __expf(-h));
}
__device__ __forceinline__ void unpack8(const uint4 v, float* o) {
  o[0] = bf2f(v.x & 0xFFFFu); o[1] = bf2f(v.x >> 16);
  o[2] = bf2f(v.y & 0xFFFFu); o[3] = bf2f(v.y >> 16);
  o[4] = bf2f(v.z & 0xFFFFu); o[5] = bf2f(v.z >> 16);
  o[6] = bf2f(v.w & 0xFFFFu); o[7] = bf2f(v.w >> 16);
}

// ----------------------------------------------------------------- aux ----
// t<150000: positions copy (float4) | next 24576: weight pre-swizzle.
__global__ __launch_bounds__(256) void aux_kernel(
    const float* __restrict__ pos,
    const float* __restrict__ W1, const float* __restrict__ W2,
    const float* __restrict__ Wu1, const float* __restrict__ Wu2,
    float* __restrict__ outpos,
    unsigned short* __restrict__ w1pq, unsigned short* __restrict__ w2t,
    unsigned short* __restrict__ wu1t, unsigned short* __restrict__ wu2b)
{
  int t = blockIdx.x * 256 + threadIdx.x;
  if (t < 150000) {
    ((float4*)outpos)[t] = ((const float4*)pos)[t];
  } else if (t < 174576) {
    const int r = t - 150000;
    if (r < 8192) {
      // w1pq: A-frags of [W1top|W1bot]^T, [mt 0..7][kk 0..1]
      const int j = r & 7, l = (r >> 3) & 15, q = (r >> 7) & 3;
      const int f = r >> 9, kk = f & 1, mt = f >> 1;
      const int k = kk * 32 + q * 8 + j;        // feat dim 0..63
      const int m = mt * 16 + l;                // pq col 0..127
      w1pq[r] = (unsigned short)f2bf(
          (m < 64) ? W1[k * 64 + m] : W1[(k + 64) * 64 + (m - 64)]);
    } else if (r < 12288) {
      // w2t: A-frags of W2^T, [mt 0..3][kk 0..1]
      const int s = r - 8192;
      const int j = s & 7, l = (s >> 3) & 15, q = (s >> 7) & 3;
      const int f = s >> 9, kk = f & 1, mt = f >> 1;
      const int k = kk * 32 + q * 8 + j;
      w2t[s] = (unsigned short)f2bf(W2[k * 64 + mt * 16 + l]);
    } else if (r < 20480) {
      // wu1t: A-frags of Wu1^T, [mt 0..3][kk 0..3]
      const int s = r - 12288;
      const int j = s & 7, l = (s >> 3) & 15, q = (s >> 7) & 3;
      const int f = s >> 9, kk = f & 3, mt = f >> 2;
      const int k = kk * 32 + q * 8 + j;        // 0..127
      wu1t[s] = (unsigned short)f2bf(Wu1[k * 64 + mt * 16 + l]);
    } else {
      // wu2b: B-frags of Wu2, [nt 0..3][kk 0..1]
      const int s = r - 20480;
      const int j = s & 7, l = (s >> 3) & 15, q = (s >> 7) & 3;
      const int f = s >> 9, kk = f & 1, nt = f >> 1;
      const int k = kk * 32 + q * 8 + j;
      wu2b[s] = (unsigned short)f2bf(Wu2[k * 64 + nt * 16 + l]);
    }
  }
}

// ------------------------------------------------------------- prep_pq ----
// One wave per 16-cell tile: read feat fp32 (B-frag layout), convert to bf16
// (write featb + keep frags), centroids for own cells, then
// [P|Q]^T = Wpq^T x X^T ; packed uint2 stores into split P / Q buffers.
__global__ __launch_bounds__(256) void prep_pq_kernel(
    const float* __restrict__ feat, const float* __restrict__ pos,
    const unsigned short* __restrict__ w1pq,
    unsigned short* __restrict__ featb, float* __restrict__ cent4,
    unsigned short* __restrict__ Pb, unsigned short* __restrict__ Qb)
{
  const int lane = threadIdx.x & 63;
  const int wid  = threadIdx.x >> 6;
  const int quad = lane >> 4;
  const int l15  = lane & 15;

  const int tile = blockIdx.x * 4 + wid;
  const bool act = (tile < 3125);
  const int  tt  = act ? tile : 3124;
  const int  cr  = tt * 16 + l15;

  // feat rows -> bf16 frags (B-layout) + featb store
  short8 xf[2];
  #pragma unroll
  for (int kk = 0; kk < 2; ++kk) {
    const float4 f0 = *(const float4*)(feat + cr * 64 + kk * 32 + quad * 8);
    const float4 f1 = *(const float4*)(feat + cr * 64 + kk * 32 + quad * 8 + 4);
    Frag v;
    v.s[0] = (short)f2bf(f0.x); v.s[1] = (short)f2bf(f0.y);
    v.s[2] = (short)f2bf(f0.z); v.s[3] = (short)f2bf(f0.w);
    v.s[4] = (short)f2bf(f1.x); v.s[5] = (short)f2bf(f1.y);
    v.s[6] = (short)f2bf(f1.z); v.s[7] = (short)f2bf(f1.w);
    xf[kk] = v.s;
    if (act) *(uint4*)(featb + cr * 64 + kk * 32 + quad * 8) = v.u;
  }

  // centroid of own 4 nodes (lanes 0..15, one cell each)
  if (act && lane < 16) {
    const float4* pp = (const float4*)(pos + 12 * cr);
    const float4 a = pp[0], b = pp[1], c = pp[2];
    float4 o;
    o.x = (a.x + a.w + b.z + c.y) * 0.25f;
    o.y = (a.y + b.x + b.w + c.z) * 0.25f;
    o.z = (a.z + b.y + c.x + c.w) * 0.25f;
    o.w = 0.f;
    ((float4*)cent4)[cr] = o;
  }

  short8 wf[8][2];
  #pragma unroll
  for (int mt = 0; mt < 8; ++mt)
    #pragma unroll
    for (int kk = 0; kk < 2; ++kk)
      wf[mt][kk] = *(const short8*)(w1pq + (((mt * 2 + kk) * 4 + quad) << 7) + l15 * 8);

  f32x4 acc[8] = {};
  #pragma unroll
  for (int kk = 0; kk < 2; ++kk)
    #pragma unroll
    for (int mt = 0; mt < 8; ++mt)
      acc[mt] = __builtin_amdgcn_mfma_f32_16x16x32_bf16(wf[mt][kk], xf[kk], acc[mt], 0, 0, 0);

  if (act) {
    #pragma unroll
    for (int mt = 0; mt < 8; ++mt) {
      uint2 pk;
      pk.x = f2bf(acc[mt][0]) | (f2bf(acc[mt][1]) << 16);
      pk.y = f2bf(acc[mt][2]) | (f2bf(acc[mt][3]) << 16);
      unsigned short* dst = (mt < 4)
          ? Pb + cr * 64 + mt * 16 + quad * 4
          : Qb + cr * 64 + (mt - 4) * 16 + quad * 4;
      *(uint2*)dst = pk;
    }
  }
}

// -------------------------------------------------------------- gather ----
// ONE WAVE PER CELL. lane = d*4 + cg: d = neighbor slot (lane>>2),
// cg = col group (lane&3) owning cols [cg*16, cg*16+16).
// All 16 neighbor-row loads issue in one round (4 lanes x 32B = 128B/row);
// geom per-lane (no pre-load shfl); mean over d via 4-stage shfl_xor butterfly.
__global__ __launch_bounds__(256) void gather_kernel(
    const unsigned short* __restrict__ Pb,
    const unsigned short* __restrict__ Qb,
    const float4* __restrict__ cent4,
    const int* __restrict__ nbr,
    const float* __restrict__ b1, const float* __restrict__ W1,
    unsigned short* __restrict__ sB)
{
  const int lane = threadIdx.x & 63;
  const int wid  = threadIdx.x >> 6;
  const int d    = lane >> 2;
  const int cg   = lane & 3;
  const int cb   = cg * 16;
  const int c    = blockIdx.x * 4 + wid;   // 12500 blocks x 4 waves = 50000

  const int nd = nbr[c * DEG + d];

  const float4 ci = cent4[c];
  const float4 cj = cent4[nd];
  const float dx = ci.x - cj.x, dy = ci.y - cj.y, dz = ci.z - cj.z;
  const float g = sqrtf(dx * dx + dy * dy + dz * dz);

  // per-lane constants & P (L1/L2-hot)
  float pc[16], wl[16];
  unpack8(*(const uint4*)(Pb + c * 64 + cb),     pc);
  unpack8(*(const uint4*)(Pb + c * 64 + cb + 8), pc + 8);
  #pragma unroll
  for (int k = 0; k < 16; k += 4) {
    const float4 bv = *(const float4*)(b1 + cb + k);
    const float4 wv = *(const float4*)(W1 + 8192 + cb + k);
    pc[k] += bv.x; pc[k+1] += bv.y; pc[k+2] += bv.z; pc[k+3] += bv.w;
    wl[k] = wv.x; wl[k+1] = wv.y; wl[k+2] = wv.z; wl[k+3] = wv.w;
  }

  float qf[16];
  unpack8(*(const uint4*)(Qb + nd * 64 + cb),     qf);
  unpack8(*(const uint4*)(Qb + nd * 64 + cb + 8), qf + 8);

  float acc[16];
  #pragma unroll
  for (int k = 0; k < 16; ++k)
    acc[k] = silu(pc[k] + qf[k] + g * wl[k]);

  // butterfly mean over d (bits 2..5 of lane)
  #pragma unroll
  for (int s = 4; s <= 32; s <<= 1)
    #pragma unroll
    for (int k = 0; k < 16; ++k)
      acc[k] += __shfl_xor(acc[k], s);

  if (lane < 4) {   // d == 0, cg = lane
    uint4 o0, o1;
    o0.x = f2bf(acc[0]*0.0625f)  | (f2bf(acc[1]*0.0625f)  << 16);
    o0.y = f2bf(acc[2]*0.0625f)  | (f2bf(acc[3]*0.0625f)  << 16);
    o0.z = f2bf(acc[4]*0.0625f)  | (f2bf(acc[5]*0.0625f)  << 16);
    o0.w = f2bf(acc[6]*0.0625f)  | (f2bf(acc[7]*0.0625f)  << 16);
    o1.x = f2bf(acc[8]*0.0625f)  | (f2bf(acc[9]*0.0625f)  << 16);
    o1.y = f2bf(acc[10]*0.0625f) | (f2bf(acc[11]*0.0625f) << 16);
    o1.z = f2bf(acc[12]*0.0625f) | (f2bf(acc[13]*0.0625f) << 16);
    o1.w = f2bf(acc[14]*0.0625f) | (f2bf(acc[15]*0.0625f) << 16);
    *(uint4*)(sB + c * 64 + cb)     = o0;
    *(uint4*)(sB + c * 64 + cb + 8) = o1;
  }
}

// ---------------------------------------------------------------- tail ----
// Per 16-cell tile: msg^T = W2^T x s^T (+b2) -> LDS; hu^T = Wu1^T x [feat|msg]^T
// (+bu1, silu) -> LDS; out = hu x Wu2 + bu2 + feat.
__global__ __launch_bounds__(256) void tail_kernel(
    const unsigned short* __restrict__ featb,
    const unsigned short* __restrict__ sB,
    const float* __restrict__ feat,
    const unsigned short* __restrict__ w2t,
    const unsigned short* __restrict__ wu1t,
    const unsigned short* __restrict__ wu2b,
    const float* __restrict__ b2, const float* __restrict__ bu1,
    const float* __restrict__ bu2,
    float* __restrict__ outf)
{
  __shared__ uint4 smem[4 * 288];   // per wave: Msg 16x144B + Hb 16x144B
  const int lane = threadIdx.x & 63;
  const int wid  = threadIdx.x >> 6;
  const int quad = lane >> 4;
  const int l15  = lane & 15;
  char* Msg = (char*)(smem + wid * 288);
  char* Hb  = Msg + 2304;

  short8 w2f[4][2];
  #pragma unroll
  for (int mt = 0; mt < 4; ++mt)
    #pragma unroll
    for (int kk = 0; kk < 2; ++kk)
      w2f[mt][kk] = *(const short8*)(w2t + (((mt * 2 + kk) * 4 + quad) << 7) + l15 * 8);
  short8 wu1f[4][4];
  #pragma unroll
  for (int mt = 0; mt < 4; ++mt)
    #pragma unroll
    for (int kk = 0; kk < 4; ++kk)
      wu1f[mt][kk] = *(const short8*)(wu1t + (((mt * 4 + kk) * 4 + quad) << 7) + l15 * 8);
  short8 wu2f[4][2];
  #pragma unroll
  for (int nt = 0; nt < 4; ++nt)
    #pragma unroll
    for (int kk = 0; kk < 2; ++kk)
      wu2f[nt][kk] = *(const short8*)(wu2b + (((nt * 2 + kk) * 4 + quad) << 7) + l15 * 8);

  f32x4 b2f[4], bu1f[4];
  #pragma unroll
  for (int mt = 0; mt < 4; ++mt) {
    b2f[mt]  = *(const f32x4*)(b2  + mt * 16 + quad * 4);
    bu1f[mt] = *(const f32x4*)(bu1 + mt * 16 + quad * 4);
  }
  float bu2v[4];
  #pragma unroll
  for (int nt = 0; nt < 4; ++nt) bu2v[nt] = bu2[nt * 16 + l15];

  const int tile = blockIdx.x * 4 + wid;
  const bool act = (tile < 3125);
  const int  tt  = act ? tile : 3124;
  const int  cr  = tt * 16 + l15;

  // stage 1: msg^T = W2^T x s^T (+b2)
  f32x4 accm[4] = {};
  #pragma unroll
  for (int kk = 0; kk < 2; ++kk) {
    const short8 bf = *(const short8*)(sB + cr * 64 + kk * 32 + quad * 8);
    #pragma unroll
    for (int mt = 0; mt < 4; ++mt)
      accm[mt] = __builtin_amdgcn_mfma_f32_16x16x32_bf16(w2f[mt][kk], bf, accm[mt], 0, 0, 0);
  }
  #pragma unroll
  for (int mt = 0; mt < 4; ++mt) {
    uint2 pk;
    pk.x = f2bf(accm[mt][0] + b2f[mt][0]) | (f2bf(accm[mt][1] + b2f[mt][1]) << 16);
    pk.y = f2bf(accm[mt][2] + b2f[mt][2]) | (f2bf(accm[mt][3] + b2f[mt][3]) << 16);
    *(uint2_a*)(Msg + l15 * 144 + mt * 32 + quad * 8) = pk;
  }
  __threadfence_block();

  // stage 2: hu^T = Wu1^T x U^T, U = [feat | msg]
  f32x4 accu[4] = {};
  #pragma unroll
  for (int kk = 0; kk < 4; ++kk) {
    short8 bf;
    if (kk < 2) {
      bf = *(const short8*)(featb + cr * 64 + kk * 32 + quad * 8);
    } else {
      HbRd t; t.u = *(const uint4_a*)(Msg + l15 * 144 + (kk - 2) * 64 + quad * 16);
      bf = t.s;
    }
    #pragma unroll
    for (int mt = 0; mt < 4; ++mt)
      accu[mt] = __builtin_amdgcn_mfma_f32_16x16x32_bf16(wu1f[mt][kk], bf, accu[mt], 0, 0, 0);
  }
  #pragma unroll
  for (int mt = 0; mt < 4; ++mt) {
    float sv[4];
    #pragma unroll
    for (int rg = 0; rg < 4; ++rg)
      sv[rg] = silu(accu[mt][rg] + bu1f[mt][rg]);
    uint2 pk;
    pk.x = f2bf(sv[0]) | (f2bf(sv[1]) << 16);
    pk.y = f2bf(sv[2]) | (f2bf(sv[3]) << 16);
    *(uint2_a*)(Hb + l15 * 144 + mt * 32 + quad * 8) = pk;
  }
  __threadfence_block();

  // stage 3: out = hu x Wu2 + bu2 + feat
  f32x4 acc2[4] = {};
  #pragma unroll
  for (int kk = 0; kk < 2; ++kk) {
    HbRd t; t.u = *(const uint4_a*)(Hb + l15 * 144 + kk * 64 + quad * 16);
    const short8 af = t.s;
    #pragma unroll
    for (int nt = 0; nt < 4; ++nt)
      acc2[nt] = __builtin_amdgcn_mfma_f32_16x16x32_bf16(af, wu2f[nt][kk], acc2[nt], 0, 0, 0);
  }
  if (act) {
    #pragma unroll
    for (int nt = 0; nt < 4; ++nt)
      #pragma unroll
      for (int rg = 0; rg < 4; ++rg) {
        const int row = tt * 16 + quad * 4 + rg;
        const int col = nt * 16 + l15;
        outf[row * 64 + col] = feat[row * 64 + col] + acc2[nt][rg] + bu2v[nt];
      }
  }
}

// -------------------------------------------------------------- launch ----
extern "C" void kernel_launch(void* const* d_in, const int* in_sizes, int n_in,
                              void* d_out, int out_size, void* d_ws, size_t ws_size,
                              hipStream_t stream)
{
  const float* feat = (const float*)d_in[0];
  const float* pos  = (const float*)d_in[1];
  const int*   nbr  = (const int*)d_in[2];
  const float* W1   = (const float*)d_in[3];
  const float* b1   = (const float*)d_in[4];
  const float* W2   = (const float*)d_in[5];
  const float* b2   = (const float*)d_in[6];
  const float* Wu1  = (const float*)d_in[7];
  const float* bu1  = (const float*)d_in[8];
  const float* Wu2  = (const float*)d_in[9];
  const float* bu2  = (const float*)d_in[10];
  float* out = (float*)d_out;

  // ws: featb 6.4M @0 | Pb 6.4M @6.4M | Qb 6.4M @12.8M | sB 6.4M @19.2M
  //   | cent4 0.8M @25.6M | swizzled weights @26.4M
  unsigned short* featb = (unsigned short*)d_ws;
  unsigned short* Pb    = (unsigned short*)((char*)d_ws + 6400000);
  unsigned short* Qb    = (unsigned short*)((char*)d_ws + 12800000);
  unsigned short* sB    = (unsigned short*)((char*)d_ws + 19200000);
  float*          cent4 = (float*)((char*)d_ws + 25600000);
  unsigned short* w1pq  = (unsigned short*)((char*)d_ws + 26400000);
  unsigned short* w2t   = (unsigned short*)((char*)d_ws + 26416384);
  unsigned short* wu1t  = (unsigned short*)((char*)d_ws + 26424576);
  unsigned short* wu2b  = (unsigned short*)((char*)d_ws + 26440960);

  aux_kernel<<<682, 256, 0, stream>>>(pos, W1, W2, Wu1, Wu2, out + 3200000,
                                      w1pq, w2t, wu1t, wu2b);
  prep_pq_kernel<<<782, 256, 0, stream>>>(feat, pos, w1pq, featb, cent4, Pb, Qb);
  gather_kernel<<<12500, 256, 0, stream>>>(Pb, Qb, (const float4*)cent4, nbr,
                                           b1, W1, sB);
  tail_kernel<<<782, 256, 0, stream>>>(featb, sB, feat, w2t, wu1t, wu2b,
                                       b2, bu1, bu2, out);
}

// Round 8
// 141.417 us; speedup vs baseline: 1.0397x; 1.0397x over previous
//
#include <hip/hip_runtime.h>

// ETNN layer, N=50000 cells, HID=64, DEG=16 neighbors, 4 nodes/cell, sp=3.
//
// Bilinear split of the per-pair message MLP:
//   x@W1 = f_i@W1[0:64] + f_j@W1[64:128] + geom*W1[128]
// -> aux    : positions passthrough + weight pre-swizzle (separate launch:
//             prep_pq reads w1pq; intra-launch block order is undefined)
// -> prep_pq: feat fp32->bf16 (featb) + centroids + P,Q = feat@[W1top|W1bot]
// -> gather : ONE WAVE PER CELL, ONE COLUMN PER LANE; neighbor ids + geom
//             broadcast via v_readlane (SGPR, scalar addressing); neighbor
//             mean accumulated IN-LANE -> zero cross-lane ops in the hot loop
// -> tail   : msg = s@W2+b2; hu = silu([feat|msg]@Wu1+bu1); out = feat+hu@Wu2+bu2
//
// MFMA layouts (HW-verified): A[m=lane&15][k=quad*8+j], B[k=quad*8+j][n=lane&15],
// D[row=quad*4+reg][col=lane&15]. Transposed stages put weights in A so D cols
// land 4-consecutive per lane (packed uint2 stores). Wave-private LDS
// round-trips ordered by __threadfence_block + may_alias types.

#define DEG 16

typedef __attribute__((ext_vector_type(8))) short short8;   // 8 bf16
typedef __attribute__((ext_vector_type(4))) float f32x4;    // MFMA acc
typedef uint2 uint2_a __attribute__((may_alias));
typedef uint4 uint4_a __attribute__((may_alias));

union HbRd { uint4_a u; short8 s; };
union Frag { short8 s; uint4 u; };

__device__ __forceinline__ unsigned f2bf(float f) {
  unsigned u = __float_as_uint(f);
  return (u + 0x7FFFu + ((u >> 16) & 1u)) >> 16;   // RNE fp32->bf16
}
__device__ __forceinline__ float bf2f(unsigned bits16) {
  return __uint_as_float(bits16 << 16);
}
__device__ __forceinline__ float silu(float h) {
  return h / (1.f + __expf(-h));
}

// ----------------------------------------------------------------- aux ----
// t<150000: positions copy (float4) | next 24576: weight pre-swizzle.
__global__ __launch_bounds__(256) void aux_kernel(
    const float* __restrict__ pos,
    const float* __restrict__ W1, const float* __restrict__ W2,
    const float* __restrict__ Wu1, const float* __restrict__ Wu2,
    float* __restrict__ outpos,
    unsigned short* __restrict__ w1pq, unsigned short* __restrict__ w2t,
    unsigned short* __restrict__ wu1t, unsigned short* __restrict__ wu2b)
{
  int t = blockIdx.x * 256 + threadIdx.x;
  if (t < 150000) {
    ((float4*)outpos)[t] = ((const float4*)pos)[t];
  } else if (t < 174576) {
    const int r = t - 150000;
    if (r < 8192) {
      // w1pq: A-frags of [W1top|W1bot]^T, [mt 0..7][kk 0..1]
      const int j = r & 7, l = (r >> 3) & 15, q = (r >> 7) & 3;
      const int f = r >> 9, kk = f & 1, mt = f >> 1;
      const int k = kk * 32 + q * 8 + j;        // feat dim 0..63
      const int m = mt * 16 + l;                // pq col 0..127
      w1pq[r] = (unsigned short)f2bf(
          (m < 64) ? W1[k * 64 + m] : W1[(k + 64) * 64 + (m - 64)]);
    } else if (r < 12288) {
      // w2t: A-frags of W2^T, [mt 0..3][kk 0..1]
      const int s = r - 8192;
      const int j = s & 7, l = (s >> 3) & 15, q = (s >> 7) & 3;
      const int f = s >> 9, kk = f & 1, mt = f >> 1;
      const int k = kk * 32 + q * 8 + j;
      w2t[s] = (unsigned short)f2bf(W2[k * 64 + mt * 16 + l]);
    } else if (r < 20480) {
      // wu1t: A-frags of Wu1^T, [mt 0..3][kk 0..3]
      const int s = r - 12288;
      const int j = s & 7, l = (s >> 3) & 15, q = (s >> 7) & 3;
      const int f = s >> 9, kk = f & 3, mt = f >> 2;
      const int k = kk * 32 + q * 8 + j;        // 0..127
      wu1t[s] = (unsigned short)f2bf(Wu1[k * 64 + mt * 16 + l]);
    } else {
      // wu2b: B-frags of Wu2, [nt 0..3][kk 0..1]
      const int s = r - 20480;
      const int j = s & 7, l = (s >> 3) & 15, q = (s >> 7) & 3;
      const int f = s >> 9, kk = f & 1, nt = f >> 1;
      const int k = kk * 32 + q * 8 + j;
      wu2b[s] = (unsigned short)f2bf(Wu2[k * 64 + nt * 16 + l]);
    }
  }
}

// ------------------------------------------------------------- prep_pq ----
// One wave per 16-cell tile: read feat fp32 (B-frag layout), convert to bf16
// (write featb + keep frags), centroids for own cells, then
// [P|Q]^T = Wpq^T x X^T ; packed uint2 stores into split P / Q buffers.
__global__ __launch_bounds__(256) void prep_pq_kernel(
    const float* __restrict__ feat, const float* __restrict__ pos,
    const unsigned short* __restrict__ w1pq,
    unsigned short* __restrict__ featb, float* __restrict__ cent4,
    unsigned short* __restrict__ Pb, unsigned short* __restrict__ Qb)
{
  const int lane = threadIdx.x & 63;
  const int wid  = threadIdx.x >> 6;
  const int quad = lane >> 4;
  const int l15  = lane & 15;

  const int tile = blockIdx.x * 4 + wid;
  const bool act = (tile < 3125);
  const int  tt  = act ? tile : 3124;
  const int  cr  = tt * 16 + l15;

  // feat rows -> bf16 frags (B-layout) + featb store
  short8 xf[2];
  #pragma unroll
  for (int kk = 0; kk < 2; ++kk) {
    const float4 f0 = *(const float4*)(feat + cr * 64 + kk * 32 + quad * 8);
    const float4 f1 = *(const float4*)(feat + cr * 64 + kk * 32 + quad * 8 + 4);
    Frag v;
    v.s[0] = (short)f2bf(f0.x); v.s[1] = (short)f2bf(f0.y);
    v.s[2] = (short)f2bf(f0.z); v.s[3] = (short)f2bf(f0.w);
    v.s[4] = (short)f2bf(f1.x); v.s[5] = (short)f2bf(f1.y);
    v.s[6] = (short)f2bf(f1.z); v.s[7] = (short)f2bf(f1.w);
    xf[kk] = v.s;
    if (act) *(uint4*)(featb + cr * 64 + kk * 32 + quad * 8) = v.u;
  }

  // centroid of own 4 nodes (lanes 0..15, one cell each)
  if (act && lane < 16) {
    const float4* pp = (const float4*)(pos + 12 * cr);
    const float4 a = pp[0], b = pp[1], c = pp[2];
    float4 o;
    o.x = (a.x + a.w + b.z + c.y) * 0.25f;
    o.y = (a.y + b.x + b.w + c.z) * 0.25f;
    o.z = (a.z + b.y + c.x + c.w) * 0.25f;
    o.w = 0.f;
    ((float4*)cent4)[cr] = o;
  }

  short8 wf[8][2];
  #pragma unroll
  for (int mt = 0; mt < 8; ++mt)
    #pragma unroll
    for (int kk = 0; kk < 2; ++kk)
      wf[mt][kk] = *(const short8*)(w1pq + (((mt * 2 + kk) * 4 + quad) << 7) + l15 * 8);

  f32x4 acc[8] = {};
  #pragma unroll
  for (int kk = 0; kk < 2; ++kk)
    #pragma unroll
    for (int mt = 0; mt < 8; ++mt)
      acc[mt] = __builtin_amdgcn_mfma_f32_16x16x32_bf16(wf[mt][kk], xf[kk], acc[mt], 0, 0, 0);

  if (act) {
    #pragma unroll
    for (int mt = 0; mt < 8; ++mt) {
      uint2 pk;
      pk.x = f2bf(acc[mt][0]) | (f2bf(acc[mt][1]) << 16);
      pk.y = f2bf(acc[mt][2]) | (f2bf(acc[mt][3]) << 16);
      unsigned short* dst = (mt < 4)
          ? Pb + cr * 64 + mt * 16 + quad * 4
          : Qb + cr * 64 + (mt - 4) * 16 + quad * 4;
      *(uint2*)dst = pk;
    }
  }
}

// -------------------------------------------------------------- gather ----
// ONE WAVE PER CELL, ONE COLUMN PER LANE. nbr ids + geom are wave-uniform
// per d: broadcast via v_readlane into SGPRs -> scalar-based coalesced
// 128B row loads, in-lane mean accumulation, zero cross-lane ops.
__global__ __launch_bounds__(256) void gather_kernel(
    const unsigned short* __restrict__ Pb,
    const unsigned short* __restrict__ Qb,
    const float4* __restrict__ cent4,
    const int* __restrict__ nbr,
    const float* __restrict__ b1, const float* __restrict__ W1,
    unsigned short* __restrict__ sB)
{
  const int lane = threadIdx.x & 63;
  const int wid  = threadIdx.x >> 6;
  const int c    = blockIdx.x * 4 + wid;   // 12500 blocks x 4 waves = 50000

  // lanes 0..15 carry the 16 neighbor ids (replicated x4 across the wave)
  const int nj = nbr[c * DEG + (lane & 15)];

  const float4 ci = cent4[c];
  const float4 cj = cent4[nj];
  const float dx = ci.x - cj.x, dy = ci.y - cj.y, dz = ci.z - cj.z;
  const float g = sqrtf(dx * dx + dy * dy + dz * dz);

  // per-column constants (lane = column)
  const float pcb = bf2f(Pb[c * 64 + lane]) + b1[lane];
  const float wl  = W1[8192 + lane];

  float acc = 0.f;
  #pragma unroll
  for (int d = 0; d < DEG; ++d) {
    const int   nd = __builtin_amdgcn_readlane(nj, d);
    const float gd = __uint_as_float(
        __builtin_amdgcn_readlane((int)__float_as_uint(g), d));
    const float qv = bf2f(Qb[nd * 64 + lane]);
    acc += silu(pcb + qv + gd * wl);
  }

  sB[c * 64 + lane] = (unsigned short)f2bf(acc * 0.0625f);
}

// ---------------------------------------------------------------- tail ----
// Per 16-cell tile: msg^T = W2^T x s^T (+b2) -> LDS; hu^T = Wu1^T x [feat|msg]^T
// (+bu1, silu) -> LDS; out = hu x Wu2 + bu2 + feat.
__global__ __launch_bounds__(256) void tail_kernel(
    const unsigned short* __restrict__ featb,
    const unsigned short* __restrict__ sB,
    const float* __restrict__ feat,
    const unsigned short* __restrict__ w2t,
    const unsigned short* __restrict__ wu1t,
    const unsigned short* __restrict__ wu2b,
    const float* __restrict__ b2, const float* __restrict__ bu1,
    const float* __restrict__ bu2,
    float* __restrict__ outf)
{
  __shared__ uint4 smem[4 * 288];   // per wave: Msg 16x144B + Hb 16x144B
  const int lane = threadIdx.x & 63;
  const int wid  = threadIdx.x >> 6;
  const int quad = lane >> 4;
  const int l15  = lane & 15;
  char* Msg = (char*)(smem + wid * 288);
  char* Hb  = Msg + 2304;

  short8 w2f[4][2];
  #pragma unroll
  for (int mt = 0; mt < 4; ++mt)
    #pragma unroll
    for (int kk = 0; kk < 2; ++kk)
      w2f[mt][kk] = *(const short8*)(w2t + (((mt * 2 + kk) * 4 + quad) << 7) + l15 * 8);
  short8 wu1f[4][4];
  #pragma unroll
  for (int mt = 0; mt < 4; ++mt)
    #pragma unroll
    for (int kk = 0; kk < 4; ++kk)
      wu1f[mt][kk] = *(const short8*)(wu1t + (((mt * 4 + kk) * 4 + quad) << 7) + l15 * 8);
  short8 wu2f[4][2];
  #pragma unroll
  for (int nt = 0; nt < 4; ++nt)
    #pragma unroll
    for (int kk = 0; kk < 2; ++kk)
      wu2f[nt][kk] = *(const short8*)(wu2b + (((nt * 2 + kk) * 4 + quad) << 7) + l15 * 8);

  f32x4 b2f[4], bu1f[4];
  #pragma unroll
  for (int mt = 0; mt < 4; ++mt) {
    b2f[mt]  = *(const f32x4*)(b2  + mt * 16 + quad * 4);
    bu1f[mt] = *(const f32x4*)(bu1 + mt * 16 + quad * 4);
  }
  float bu2v[4];
  #pragma unroll
  for (int nt = 0; nt < 4; ++nt) bu2v[nt] = bu2[nt * 16 + l15];

  const int tile = blockIdx.x * 4 + wid;
  const bool act = (tile < 3125);
  const int  tt  = act ? tile : 3124;
  const int  cr  = tt * 16 + l15;

  // stage 1: msg^T = W2^T x s^T (+b2)
  f32x4 accm[4] = {};
  #pragma unroll
  for (int kk = 0; kk < 2; ++kk) {
    const short8 bf = *(const short8*)(sB + cr * 64 + kk * 32 + quad * 8);
    #pragma unroll
    for (int mt = 0; mt < 4; ++mt)
      accm[mt] = __builtin_amdgcn_mfma_f32_16x16x32_bf16(w2f[mt][kk], bf, accm[mt], 0, 0, 0);
  }
  #pragma unroll
  for (int mt = 0; mt < 4; ++mt) {
    uint2 pk;
    pk.x = f2bf(accm[mt][0] + b2f[mt][0]) | (f2bf(accm[mt][1] + b2f[mt][1]) << 16);
    pk.y = f2bf(accm[mt][2] + b2f[mt][2]) | (f2bf(accm[mt][3] + b2f[mt][3]) << 16);
    *(uint2_a*)(Msg + l15 * 144 + mt * 32 + quad * 8) = pk;
  }
  __threadfence_block();

  // stage 2: hu^T = Wu1^T x U^T, U = [feat | msg]
  f32x4 accu[4] = {};
  #pragma unroll
  for (int kk = 0; kk < 4; ++kk) {
    short8 bf;
    if (kk < 2) {
      bf = *(const short8*)(featb + cr * 64 + kk * 32 + quad * 8);
    } else {
      HbRd t; t.u = *(const uint4_a*)(Msg + l15 * 144 + (kk - 2) * 64 + quad * 16);
      bf = t.s;
    }
    #pragma unroll
    for (int mt = 0; mt < 4; ++mt)
      accu[mt] = __builtin_amdgcn_mfma_f32_16x16x32_bf16(wu1f[mt][kk], bf, accu[mt], 0, 0, 0);
  }
  #pragma unroll
  for (int mt = 0; mt < 4; ++mt) {
    float sv[4];
    #pragma unroll
    for (int rg = 0; rg < 4; ++rg)
      sv[rg] = silu(accu[mt][rg] + bu1f[mt][rg]);
    uint2 pk;
    pk.x = f2bf(sv[0]) | (f2bf(sv[1]) << 16);
    pk.y = f2bf(sv[2]) | (f2bf(sv[3]) << 16);
    *(uint2_a*)(Hb + l15 * 144 + mt * 32 + quad * 8) = pk;
  }
  __threadfence_block();

  // stage 3: out = hu x Wu2 + bu2 + feat
  f32x4 acc2[4] = {};
  #pragma unroll
  for (int kk = 0; kk < 2; ++kk) {
    HbRd t; t.u = *(const uint4_a*)(Hb + l15 * 144 + kk * 64 + quad * 16);
    const short8 af = t.s;
    #pragma unroll
    for (int nt = 0; nt < 4; ++nt)
      acc2[nt] = __builtin_amdgcn_mfma_f32_16x16x32_bf16(af, wu2f[nt][kk], acc2[nt], 0, 0, 0);
  }
  if (act) {
    #pragma unroll
    for (int nt = 0; nt < 4; ++nt)
      #pragma unroll
      for (int rg = 0; rg < 4; ++rg) {
        const int row = tt * 16 + quad * 4 + rg;
        const int col = nt * 16 + l15;
        outf[row * 64 + col] = feat[row * 64 + col] + acc2[nt][rg] + bu2v[nt];
      }
  }
}

// -------------------------------------------------------------- launch ----
extern "C" void kernel_launch(void* const* d_in, const int* in_sizes, int n_in,
                              void* d_out, int out_size, void* d_ws, size_t ws_size,
                              hipStream_t stream)
{
  const float* feat = (const float*)d_in[0];
  const float* pos  = (const float*)d_in[1];
  const int*   nbr  = (const int*)d_in[2];
  const float* W1   = (const float*)d_in[3];
  const float* b1   = (const float*)d_in[4];
  const float* W2   = (const float*)d_in[5];
  const float* b2   = (const float*)d_in[6];
  const float* Wu1  = (const float*)d_in[7];
  const float* bu1  = (const float*)d_in[8];
  const float* Wu2  = (const float*)d_in[9];
  const float* bu2  = (const float*)d_in[10];
  float* out = (float*)d_out;

  // ws: featb 6.4M @0 | Pb 6.4M @6.4M | Qb 6.4M @12.8M | sB 6.4M @19.2M
  //   | cent4 0.8M @25.6M | swizzled weights @26.4M
  unsigned short* featb = (unsigned short*)d_ws;
  unsigned short* Pb    = (unsigned short*)((char*)d_ws + 6400000);
  unsigned short* Qb    = (unsigned short*)((char*)d_ws + 12800000);
  unsigned short* sB    = (unsigned short*)((char*)d_ws + 19200000);
  float*          cent4 = (float*)((char*)d_ws + 25600000);
  unsigned short* w1pq  = (unsigned short*)((char*)d_ws + 26400000);
  unsigned short* w2t   = (unsigned short*)((char*)d_ws + 26416384);
  unsigned short* wu1t  = (unsigned short*)((char*)d_ws + 26424576);
  unsigned short* wu2b  = (unsigned short*)((char*)d_ws + 26440960);

  aux_kernel<<<682, 256, 0, stream>>>(pos, W1, W2, Wu1, Wu2, out + 3200000,
                                      w1pq, w2t, wu1t, wu2b);
  prep_pq_kernel<<<782, 256, 0, stream>>>(feat, pos, w1pq, featb, cent4, Pb, Qb);
  gather_kernel<<<12500, 256, 0, stream>>>(Pb, Qb, (const float4*)cent4, nbr,
                                           b1, W1, sB);
  tail_kernel<<<782, 256, 0, stream>>>(featb, sB, feat, w2t, wu1t, wu2b,
                                       b2, bu1, bu2, out);
}